// Round 9
// baseline (244.601 us; speedup 1.0000x reference)
//
#include <hip/hip_runtime.h>

#define HID 64
#define TT  128
#define NROWS 8192
#define NBLK (NROWS / 32)   // 256 blocks x 32 rows (4 waves x 8 rows); 1 block/CU
#define LOG2E 1.44269504088896f

typedef _Float16 half8 __attribute__((ext_vector_type(8)));
typedef float    f32x4 __attribute__((ext_vector_type(4)));
typedef int      int4v __attribute__((ext_vector_type(4)));

// R9: j-complete waves, 8 rows/wave, register-only h exchange via ds_bpermute.
// Cols 0-7 = rows, 8-15 = replicas (rep splits activation e-pairs).
// No barrier, no LDS h round-trip, no sort; single dispatch.
__global__ __launch_bounds__(256, 1) void gru_fused(
    const int* __restrict__ actor_ids, const int* __restrict__ action_ids,
    const int* __restrict__ street_ids, const float* __restrict__ bet,
    const int* __restrict__ mask,
    const float* __restrict__ E_actor, const float* __restrict__ E_action,
    const float* __restrict__ E_street, const float* __restrict__ W_proj,
    const float* __restrict__ b_proj, const float* __restrict__ W_ih,
    const float* __restrict__ b_ih, const float* __restrict__ W_hh,
    const float* __restrict__ b_hh, float* __restrict__ out)
{
    __shared__ __align__(16) union {
        _Float16 wfs[192][32];     // startup: fused W_f f16 (scaled), bias at k=21
        int pb[TT][33];            // main: ids|bet16 per (t, row 0..31)
    } A;
    __shared__ __align__(16) _Float16 embl[144];

    const int tid = threadIdx.x;
    const int w   = tid >> 6;        // wave -> rows 8w..8w+7
    const int l   = tid & 63;
    const int u   = l >> 4;          // k-quad
    const int cc  = l & 15;          // MFMA col
    const int rep = cc >> 3;         // replica: e-pair {2rep, 2rep+1}
    const int r   = cc & 7;          // row within wave
    const int g   = blockIdx.x;
    const bool lohalf = (l < 32);    // u<2

    // embedding rows: 0..6 actor, 7..10 action, 11..15 street(+pad), 16 zero
    for (int i = tid; i < 136; i += 256) {
        int rr = i >> 3, m = i & 7;
        float v = 0.f;
        if (rr < 7)       v = E_actor[rr * 8 + m];
        else if (rr < 11) v = E_action[(rr - 7) * 8 + m];
        else if (rr < 16) v = (m < 4) ? E_street[(rr - 11) * 4 + m] : 0.f;
        embl[i] = (_Float16)v;
    }

    // ---- startup: fused input weights (f16, scaled); total bias rides k=21 ----
    if (tid < 192) {
        const int j = tid;
        float wf[21];
        #pragma unroll
        for (int m = 0; m < 21; m++) wf[m] = 0.f;
        float bf = b_ih[j];
        for (int k = 0; k < 32; k++) {
            const float wv = W_ih[j * 32 + k];
            bf += wv * b_proj[k];
            #pragma unroll
            for (int m = 0; m < 21; m++) wf[m] += wv * W_proj[k * 21 + m];
        }
        if (j < 128) bf += b_hh[j];          // b_hh(n) stays h-side (inside r*(.))
        const float s = (j < 128) ? LOG2E : 2.f * LOG2E;
        #pragma unroll
        for (int m = 0; m < 21; m++) A.wfs[j][m] = (_Float16)(wf[m] * s);
        A.wfs[j][21] = (_Float16)(bf * s);
        #pragma unroll
        for (int m = 22; m < 32; m++) A.wfs[j][m] = (_Float16)0.f;
    }
    __syncthreads();

    // ---- fragments: Af[12] (x), Ah[12][2] (h), biasH[4] ----
    // A[m=lane&15][k=(lane>>4)*8+pos]; tile jt covers j = 16jt+cc.
    // Tiles 0-3 r, 4-7 z, 8-11 n.
    half8 Af[12], Ah[12][2];
    #pragma unroll
    for (int jt = 0; jt < 12; jt++) {
        const int jr = jt * 16 + cc;
        Af[jt] = *(const half8*)&A.wfs[jr][u * 8];
        const float s = (jt < 8) ? LOG2E : 2.f * LOG2E;
        #pragma unroll
        for (int kt = 0; kt < 2; kt++) {
            _Float16 w8[8];
            #pragma unroll
            for (int m = 0; m < 8; m++)
                w8[m] = (_Float16)(W_hh[jr * HID + kt * 32 + u * 8 + m] * s);
            Ah[jt][kt] = *(half8*)w8;
        }
    }
    f32x4 biasH[4];
    #pragma unroll
    for (int T = 0; T < 4; T++)
        #pragma unroll
        for (int e = 0; e < 4; e++)
            biasH[T][e] = b_hh[128 + 16 * T + 4 * u + e] * (2.f * LOG2E);
    __syncthreads();   // wfs dead; arena becomes pb. LAST barrier.

    // ---- stage pb (each wave its own 8 rows) + in-wave lengths ----
    int cnt = 0;
    {
        const int srow = tid >> 3, tl = tid & 7;     // wave w: srow 8w..8w+7
        const int base = (g * 32 + srow) * TT;
        #pragma unroll
        for (int i = 0; i < 16; i++) {
            const int t = tl + 8 * i;
            const int a = actor_ids[base + t], ac = action_ids[base + t];
            const int s = street_ids[base + t];
            const _Float16 f16v = (_Float16)bet[base + t];
            const unsigned fb = (unsigned)*(const unsigned short*)&f16v;
            A.pb[t][srow] = (int)(a | (ac << 3) | (s << 5) | (fb << 16));
            cnt += (mask[base + t] != 0);
        }
        cnt += __shfl_xor(cnt, 1);
        cnt += __shfl_xor(cnt, 2);
        cnt += __shfl_xor(cnt, 4);                   // lane l holds L(row l>>3)
    }
    int Lmax = cnt;
    { int o = __shfl_xor(Lmax, 8);  Lmax = o > Lmax ? o : Lmax; }
    { int o = __shfl_xor(Lmax, 16); Lmax = o > Lmax ? o : Lmax; }
    { int o = __shfl_xor(Lmax, 32); Lmax = o > Lmax ? o : Lmax; }
    const int Ln = __shfl(cnt, 8 * r);               // this lane's row length

    // bpermute addresses (bytes): slot s pulls lane 16*(2(u&1)+(s>>1))+8(s&1)+r
    int xaddr[4];
    #pragma unroll
    for (int s = 0; s < 4; s++)
        xaddr[s] = 4 * (16 * (2 * (u & 1) + (s >> 1)) + 8 * (s & 1) + r);

    const bool isu2 = (u == 2);
    const int sh = (u == 1) ? 3 : (u == 2) ? 5 : 0;
    const int mk = (u == 1) ? 3 : (u == 3) ? 0 : 7;
    const int of = (u == 1) ? 7 : (u == 2) ? 11 : (u == 3) ? 16 : 0;
    const int col = 8 * w + r;                       // pb column

    const f32x4 zero4 = {0.f, 0.f, 0.f, 0.f};
    float hc[8] = {0.f, 0.f, 0.f, 0.f, 0.f, 0.f, 0.f, 0.f};
    int b00 = 0, b01 = 0, b02 = 0, b03 = 0;          // Bh0 dwords (h=0)
    int b10 = 0, b11 = 0, b12 = 0, b13 = 0;          // Bh1 dwords

    // Bf pipeline: Bf = step t, Bfn = step t+1
    half8 Bf, Bfn;
    {
        const int p0 = A.pb[0][col];
        Bf = *(const half8*)&embl[(((p0 >> sh) & mk) + of) * 8];
        uint4* bq = (uint4*)&Bf;
        bq->z = isu2 ? (((unsigned)p0 >> 16) | 0x3C000000u) : bq->z; // {bet,1.0}
        const int p1 = A.pb[1][col];
        Bfn = *(const half8*)&embl[(((p1 >> sh) & mk) + of) * 8];
        uint4* bq1 = (uint4*)&Bfn;
        bq1->z = isu2 ? (((unsigned)p1 >> 16) | 0x3C000000u) : bq1->z;
    }

    for (int t = 0; t < Lmax; t++) {
        int4v bi0; bi0[0] = b00; bi0[1] = b01; bi0[2] = b02; bi0[3] = b03;
        int4v bi1; bi1[0] = b10; bi1[1] = b11; bi1[2] = b12; bi1[3] = b13;
        const half8 Bh0 = __builtin_bit_cast(half8, bi0);
        const half8 Bh1 = __builtin_bit_cast(half8, bi1);
        const int t2 = (t + 2 < TT) ? t + 2 : TT - 1;
        const int p2 = A.pb[t2][col];

        // x-side: 12 tiles, C=0 (bias rides k=21); independent of exchange
        f32x4 x[12];
        #pragma unroll
        for (int jt = 0; jt < 12; jt++)
            x[jt] = __builtin_amdgcn_mfma_f32_16x16x32_f16(Af[jt], Bf, zero4, 0, 0, 0);
        // h-side r,z: chained through x
        f32x4 acc[8];
        #pragma unroll
        for (int jt = 0; jt < 8; jt++) {
            f32x4 t0 = __builtin_amdgcn_mfma_f32_16x16x32_f16(Ah[jt][0], Bh0, x[jt], 0, 0, 0);
            acc[jt]  = __builtin_amdgcn_mfma_f32_16x16x32_f16(Ah[jt][1], Bh1, t0, 0, 0, 0);
        }
        // h-side n: C = b_hh(n)
        f32x4 hn[4];
        #pragma unroll
        for (int T = 0; T < 4; T++) {
            f32x4 t0 = __builtin_amdgcn_mfma_f32_16x16x32_f16(Ah[8 + T][0], Bh0, biasH[T], 0, 0, 0);
            hn[T]    = __builtin_amdgcn_mfma_f32_16x16x32_f16(Ah[8 + T][1], Bh1, t0, 0, 0, 0);
        }

        // gather Bf(t+2) under MFMA latency
        half8 Bf2;
        {
            Bf2 = *(const half8*)&embl[(((p2 >> sh) & mk) + of) * 8];
            uint4* bq = (uint4*)&Bf2;
            bq->z = isu2 ? (((unsigned)p2 >> 16) | 0x3C000000u) : bq->z;
        }

        // activation: 8 h/lane (e-pair by rep); pack 4 dwords
        const bool live = (t < Ln);
        int hd0, hd1, hd2, hd3;
        #pragma unroll
        for (int T = 0; T < 4; T++) {
            const f32x4 aR4 = acc[T], aZ4 = acc[4 + T], xn4 = x[8 + T], hn4 = hn[T];
            _Float16 pk[2];
            #pragma unroll
            for (int d = 0; d < 2; d++) {
                const float aRv = rep ? aR4[2 + d] : aR4[d];
                const float aZv = rep ? aZ4[2 + d] : aZ4[d];
                const float xnv = rep ? xn4[2 + d] : xn4[d];
                const float hnv = rep ? hn4[2 + d] : hn4[d];
                const float rr = __builtin_amdgcn_rcpf(1.f + __builtin_amdgcn_exp2f(-aRv));
                const float zz = __builtin_amdgcn_rcpf(1.f + __builtin_amdgcn_exp2f(-aZv));
                const float y2 = xnv + rr * hnv;          // 2*log2e*y
                const float nn = 1.f - 2.f * __builtin_amdgcn_rcpf(1.f + __builtin_amdgcn_exp2f(y2));
                const float hv = nn + zz * (hc[2 * T + d] - nn);
                hc[2 * T + d] = live ? hv : hc[2 * T + d];
                pk[d] = (_Float16)hc[2 * T + d];
            }
            const int pki = (int)((unsigned)*(const unsigned short*)&pk[0] |
                                  ((unsigned)*(const unsigned short*)&pk[1] << 16));
            if (T == 0) hd0 = pki; else if (T == 1) hd1 = pki;
            else if (T == 2) hd2 = pki; else hd3 = pki;
        }

        // register-only exchange: consumer pulls its 8 Bh dwords
        #pragma unroll
        for (int s = 0; s < 4; s++) {
            const int a = xaddr[s];
            const int ta = __builtin_amdgcn_ds_bpermute(a, hd0);
            const int tb = __builtin_amdgcn_ds_bpermute(a, hd1);
            const int tc = __builtin_amdgcn_ds_bpermute(a, hd2);
            const int td = __builtin_amdgcn_ds_bpermute(a, hd3);
            const int v0 = lohalf ? ta : tb;     // Bh0: hd[u'>>1]
            const int v1 = lohalf ? tc : td;     // Bh1: hd[2+(u'>>1)]
            if (s == 0) { b00 = v0; b10 = v1; }
            else if (s == 1) { b01 = v0; b11 = v1; }
            else if (s == 2) { b02 = v0; b12 = v1; }
            else { b03 = v0; b13 = v1; }
        }

        Bf = Bfn; Bfn = Bf2;
    }

    // output: lane's 8 h at i = 16T + 4u + 2rep + {0,1}
    const int grow = g * 32 + 8 * w + r;
    #pragma unroll
    for (int T = 0; T < 4; T++)
        *(float2*)&out[grow * HID + 16 * T + 4 * u + 2 * rep] =
            make_float2(hc[2 * T], hc[2 * T + 1]);
}

extern "C" void kernel_launch(void* const* d_in, const int* in_sizes, int n_in,
                              void* d_out, int out_size, void* d_ws, size_t ws_size,
                              hipStream_t stream) {
    const int*   actor_ids  = (const int*)d_in[0];
    const int*   action_ids = (const int*)d_in[1];
    const int*   street_ids = (const int*)d_in[2];
    const float* bet        = (const float*)d_in[3];
    const int*   vmask      = (const int*)d_in[4];
    const float* E_actor    = (const float*)d_in[5];
    const float* E_action   = (const float*)d_in[6];
    const float* E_street   = (const float*)d_in[7];
    const float* W_proj     = (const float*)d_in[8];
    const float* b_proj     = (const float*)d_in[9];
    const float* W_ih       = (const float*)d_in[10];
    const float* W_hh       = (const float*)d_in[11];
    const float* b_ih       = (const float*)d_in[12];
    const float* b_hh       = (const float*)d_in[13];
    float*       out        = (float*)d_out;

    gru_fused<<<NBLK, 256, 0, stream>>>(actor_ids, action_ids, street_ids, bet,
                                        vmask, E_actor, E_action, E_street,
                                        W_proj, b_proj, W_ih, b_ih, W_hh, b_hh,
                                        out);
}

// Round 10
// 160.263 us; speedup vs baseline: 1.5262x; 1.5262x over previous
//
#include <hip/hip_runtime.h>

#define HID 64
#define TT  128
#define NROWS 8192
#define NGRP (NROWS / 8)    // 1024 blocks of 8 rows; 4 blocks/CU
#define LOG2E 1.44269504088896f

typedef _Float16 half8 __attribute__((ext_vector_type(8)));
typedef float    f32x4 __attribute__((ext_vector_type(4)));

// ---------- pre-pass: length-sort rows into balanced 8-row groups ----------
// ws layout (ints): lens[8192] | perm[8192]

__global__ void k_len(const int* __restrict__ mask, int* __restrict__ lens) {
    const int row = blockIdx.x * 4 + (threadIdx.x >> 6);
    const int l   = threadIdx.x & 63;
    const int* mrow = mask + row * TT;
    int c = (mrow[l] != 0) + (mrow[l + 64] != 0);
    #pragma unroll
    for (int k = 32; k >= 1; k >>= 1) c += __shfl_xor(c, k);
    if (l == 0) lens[row] = c;
}

// Single block: LDS histogram -> prefix -> scatter. Descending rank d ->
// 8-row group g8 = d/8; slots {c, 511-c, 512+c, 1023-c} land on CU c.
__global__ __launch_bounds__(1024) void k_sort(const int* __restrict__ lens,
                                               int* __restrict__ perm) {
    __shared__ int hist[TT + 1];
    __shared__ int offs[TT + 1];
    const int tid = threadIdx.x;
    if (tid <= TT) hist[tid] = 0;
    __syncthreads();
    int myL[8];
    #pragma unroll
    for (int i = 0; i < 8; i++) {
        myL[i] = lens[tid + 1024 * i];
        atomicAdd(&hist[myL[i]], 1);
    }
    __syncthreads();
    if (tid <= TT) {
        int s = 0;
        for (int j = 0; j < tid; j++) s += hist[j];
        offs[tid] = s;
    }
    __syncthreads();
    #pragma unroll
    for (int i = 0; i < 8; i++) {
        const int pos = atomicAdd(&offs[myL[i]], 1);      // ascending rank
        const int d   = NROWS - 1 - pos;                  // descending rank
        const int g8  = d >> 3, r = d & 7;
        int b;
        if      (g8 < 256) b = g8;
        else if (g8 < 512) b = 256 + (511 - g8);
        else if (g8 < 768) b = 512 + (g8 - 512);
        else               b = 768 + (1023 - g8);
        perm[b * 8 + r] = tid + 1024 * i;
    }
}

// ---------- main GRU: R7 structure + 2x unroll + bank-replicated embl ----------
// 8-row blocks, cols 0-7 rows / 8-15 dups; lane hf=cc>>3 activates e-pair.
__global__ __launch_bounds__(256, 4) void gru_fused(
    const int* __restrict__ actor_ids, const int* __restrict__ action_ids,
    const int* __restrict__ street_ids, const float* __restrict__ bet,
    const float* __restrict__ E_actor, const float* __restrict__ E_action,
    const float* __restrict__ E_street, const float* __restrict__ W_proj,
    const float* __restrict__ b_proj, const float* __restrict__ W_ih,
    const float* __restrict__ b_ih, const float* __restrict__ W_hh,
    const float* __restrict__ b_hh, const int* __restrict__ perm,
    const int* __restrict__ lens, float* __restrict__ out)
{
    __shared__ __align__(16) union {
        float wfs[192][32];                           // startup: fused W_f (scaled)
        struct {
            int pb[TT][9];                            // ids|bet16, 8 rows + pad
            __align__(16) _Float16 hb[2][8][72];      // h f16 dbuf, stride 72
            int Lsh[8];
            int Psh[8];
        } c;
    } A;
    // 8 bank-quad-offset copies (copy stride 272B -> base quad = c mod 8):
    // lane uses copy l&7 so the data-dependent gather is conflict-free.
    __shared__ __align__(16) _Float16 embl[8][136];
    __shared__ float bfs[192];                        // raw fused bias b_f

    const int tid = threadIdx.x;
    const int wv  = tid >> 6;        // wave = hid quarter (j-split)
    const int l   = tid & 63;
    const int q   = l >> 4;          // k-quad / j-subquad
    const int cc  = l & 15;          // MFMA col
    const int cr  = cc & 7;          // batch row within group
    const int hf  = cc >> 3;         // activation element half
    const int g   = blockIdx.x;
    const int ec  = l & 7;           // embl copy for this lane

    // embedding rows: 0..6 actor, 7..10 action, 11..15 street(+pad), 16 zero
    for (int i = tid; i < 136; i += 256) {
        int r = i >> 3, m = i & 7;
        float v = 0.f;
        if (r < 7)       v = E_actor[r * 8 + m];
        else if (r < 11) v = E_action[(r - 7) * 8 + m];
        else if (r < 16) v = (m < 4) ? E_street[(r - 11) * 4 + m] : 0.f;
        const _Float16 hv = (_Float16)v;
        #pragma unroll
        for (int c8 = 0; c8 < 8; c8++) embl[c8][i] = hv;
    }

    // ---- startup: fused input weights into LDS ----
    if (tid < 192) {
        const int j = tid;
        float wf[21];
        #pragma unroll
        for (int m = 0; m < 21; m++) wf[m] = 0.f;
        float bf = b_ih[j];
        for (int k = 0; k < 32; k++) {
            const float w = W_ih[j * 32 + k];
            bf += w * b_proj[k];
            #pragma unroll
            for (int m = 0; m < 21; m++) wf[m] += w * W_proj[k * 21 + m];
        }
        const float s = (j < 128) ? LOG2E : 2.f * LOG2E;
        #pragma unroll
        for (int m = 0; m < 21; m++) A.wfs[j][m] = wf[m] * s;
        #pragma unroll
        for (int m = 21; m < 32; m++) A.wfs[j][m] = 0.f;
        bfs[j] = bf;
    }
    __syncthreads();

    // ---- extract per-lane A-fragments + biases (registers) ----
    half8 Af[3], Ah[3][2];
    {
        const int m16 = l & 15, kq = l >> 4;
        #pragma unroll
        for (int g3 = 0; g3 < 3; g3++) {
            const int jr = g3 * 64 + wv * 16 + m16;
            _Float16 v[8];
            #pragma unroll
            for (int m = 0; m < 8; m++) v[m] = (_Float16)A.wfs[jr][kq * 8 + m];
            Af[g3] = *(half8*)v;
            const float s = (g3 < 2) ? LOG2E : 2.f * LOG2E;
            #pragma unroll
            for (int kt = 0; kt < 2; kt++) {
                _Float16 w[8];
                #pragma unroll
                for (int m = 0; m < 8; m++)
                    w[m] = (_Float16)(W_hh[jr * HID + kt * 32 + kq * 8 + m] * s);
                Ah[g3][kt] = *(half8*)w;
            }
        }
    }
    f32x4 biasR, biasZ, biasX, biasH;
    #pragma unroll
    for (int e = 0; e < 4; e++) {
        const int idx = 16 * wv + 4 * q + e;
        biasR[e] = (bfs[idx]      + b_hh[idx])      * LOG2E;
        biasZ[e] = (bfs[64 + idx] + b_hh[64 + idx]) * LOG2E;
        biasX[e] = bfs[128 + idx]  * (2.f * LOG2E);
        biasH[e] = b_hh[128 + idx] * (2.f * LOG2E);
    }
    __syncthreads();   // wfs dead; arena becomes pb/hb

    // ---- stage pb via perm (32 thr/row), zero hb, fetch lengths ----
    for (int i = tid; i < 2 * 8 * 72 / 2; i += 256) ((int*)A.c.hb)[i] = 0;
    {
        const int r = tid >> 5, tl = tid & 31;
        const int prow = perm[g * 8 + r];
        const int base = prow * TT;
        #pragma unroll
        for (int i = 0; i < 4; i++) {
            const int t = tl + 32 * i;
            const int a = actor_ids[base + t], c = action_ids[base + t];
            const int s = street_ids[base + t];
            const _Float16 f16 = (_Float16)bet[base + t];
            const unsigned fb = (unsigned)*(const unsigned short*)&f16;
            A.c.pb[t][r] = (int)(a | (c << 3) | (s << 5) | (fb << 16));
        }
        if (tl == 0) { A.c.Lsh[r] = lens[prow]; A.c.Psh[r] = prow; }
    }
    __syncthreads();

    const int Ln = A.c.Lsh[cr];
    int Lmax = Ln;
    { int o = __shfl_xor(Lmax, 1); Lmax = o > Lmax ? o : Lmax; }
    { int o = __shfl_xor(Lmax, 2); Lmax = o > Lmax ? o : Lmax; }
    { int o = __shfl_xor(Lmax, 4); Lmax = o > Lmax ? o : Lmax; }

    const bool isq2 = (q == 2);
    const int sh = (q == 1) ? 3 : (q == 2) ? 5 : 0;
    const int mk = (q == 1) ? 3 : (q == 3) ? 0 : 7;
    const int of = (q == 1) ? 7 : (q == 2) ? 11 : (q == 3) ? 16 : 0;

    const int j0 = 16 * wv + 4 * q + 2 * hf;
    float h0 = 0.f, h1 = 0.f;
    const f32x4 zero4 = {0.f, 0.f, 0.f, 0.f};

    // ---- prologue: Bf(0), Bf(1); x(0) ----
    half8 BfA, BfB;
    {
        const int p0 = A.c.pb[0][cr];
        BfA = *(const half8*)&embl[ec][(((p0 >> sh) & mk) + of) * 8];
        uint4* b0 = (uint4*)&BfA;
        b0->z = isq2 ? ((unsigned)p0 >> 16) : b0->z;   // {bet16, 0} at k=20,21
        const int p1 = A.c.pb[1][cr];
        BfB = *(const half8*)&embl[ec][(((p1 >> sh) & mk) + of) * 8];
        uint4* b1 = (uint4*)&BfB;
        b1->z = isq2 ? ((unsigned)p1 >> 16) : b1->z;
    }
    f32x4 xR0 = __builtin_amdgcn_mfma_f32_16x16x32_f16(Af[0], BfA, biasR, 0, 0, 0);
    f32x4 xZ0 = __builtin_amdgcn_mfma_f32_16x16x32_f16(Af[1], BfA, biasZ, 0, 0, 0);
    f32x4 xX0 = __builtin_amdgcn_mfma_f32_16x16x32_f16(Af[2], BfA, biasX, 0, 0, 0);
    f32x4 xR1, xZ1, xX1;

    // activation macro: consumes aR,aZ,aH,aX; updates h0,h1; writes hb[WB]
    #define ACT_WRITE(aR_, aZ_, aH_, aX_, LIVE_, WB_)                              \
    {                                                                              \
        const float vR0 = hf ? aR_[2] : aR_[0], vR1 = hf ? aR_[3] : aR_[1];        \
        const float vZ0 = hf ? aZ_[2] : aZ_[0], vZ1 = hf ? aZ_[3] : aZ_[1];        \
        const float vH0 = hf ? aH_[2] : aH_[0], vH1 = hf ? aH_[3] : aH_[1];        \
        const float vX0 = hf ? aX_[2] : aX_[0], vX1 = hf ? aX_[3] : aX_[1];        \
        const float r0 = __builtin_amdgcn_rcpf(1.f + __builtin_amdgcn_exp2f(-vR0));\
        const float z0 = __builtin_amdgcn_rcpf(1.f + __builtin_amdgcn_exp2f(-vZ0));\
        const float y0 = vX0 + r0 * vH0;                                           \
        const float n0 = 1.f - 2.f * __builtin_amdgcn_rcpf(1.f + __builtin_amdgcn_exp2f(y0)); \
        const float hv0 = n0 + z0 * (h0 - n0);                                     \
        h0 = (LIVE_) ? hv0 : h0;                                                   \
        const float r1 = __builtin_amdgcn_rcpf(1.f + __builtin_amdgcn_exp2f(-vR1));\
        const float z1 = __builtin_amdgcn_rcpf(1.f + __builtin_amdgcn_exp2f(-vZ1));\
        const float y1 = vX1 + r1 * vH1;                                           \
        const float n1 = 1.f - 2.f * __builtin_amdgcn_rcpf(1.f + __builtin_amdgcn_exp2f(y1)); \
        const float hv1 = n1 + z1 * (h1 - n1);                                     \
        h1 = (LIVE_) ? hv1 : h1;                                                   \
        const _Float16 a16 = (_Float16)h0, b16 = (_Float16)h1;                     \
        const unsigned pk = (unsigned)*(const unsigned short*)&a16 |               \
                            ((unsigned)*(const unsigned short*)&b16 << 16);        \
        *(unsigned*)&A.c.hb[WB_][cr][j0] = pk;                                     \
    }

    for (int t = 0; t < Lmax; t += 2) {
        // ======== step A (even t): read hb[0], write hb[1] ========
        {
            const half8 Bh0 = *(const half8*)&A.c.hb[0][cr][q * 8];
            const half8 Bh1 = *(const half8*)&A.c.hb[0][cr][32 + q * 8];
            const int t2 = (t + 2 < TT) ? t + 2 : TT - 1;
            const int p2 = A.c.pb[t2][cr];

            f32x4 aRa = __builtin_amdgcn_mfma_f32_16x16x32_f16(Ah[0][0], Bh0, xR0, 0, 0, 0);
            f32x4 aRb = __builtin_amdgcn_mfma_f32_16x16x32_f16(Ah[0][1], Bh1, zero4, 0, 0, 0);
            f32x4 aZ = __builtin_amdgcn_mfma_f32_16x16x32_f16(Ah[1][0], Bh0, xZ0, 0, 0, 0);
            aZ = __builtin_amdgcn_mfma_f32_16x16x32_f16(Ah[1][1], Bh1, aZ, 0, 0, 0);
            f32x4 aH = __builtin_amdgcn_mfma_f32_16x16x32_f16(Ah[2][0], Bh0, biasH, 0, 0, 0);
            aH = __builtin_amdgcn_mfma_f32_16x16x32_f16(Ah[2][1], Bh1, aH, 0, 0, 0);
            const f32x4 aR = aRa + aRb;

            // x(t+1) from BfB (register-only B)
            xR1 = __builtin_amdgcn_mfma_f32_16x16x32_f16(Af[0], BfB, biasR, 0, 0, 0);
            xZ1 = __builtin_amdgcn_mfma_f32_16x16x32_f16(Af[1], BfB, biasZ, 0, 0, 0);
            xX1 = __builtin_amdgcn_mfma_f32_16x16x32_f16(Af[2], BfB, biasX, 0, 0, 0);

            // gather Bf(t+2) -> BfA (old BfA already consumed)
            BfA = *(const half8*)&embl[ec][(((p2 >> sh) & mk) + of) * 8];
            uint4* bq = (uint4*)&BfA;
            bq->z = isq2 ? ((unsigned)p2 >> 16) : bq->z;

            ACT_WRITE(aR, aZ, aH, xX0, t < Ln, 1);
        }
        __syncthreads();
        // ======== step B (t+1): read hb[1], write hb[0] ========
        {
            const half8 Bh0 = *(const half8*)&A.c.hb[1][cr][q * 8];
            const half8 Bh1 = *(const half8*)&A.c.hb[1][cr][32 + q * 8];
            const int t3 = (t + 3 < TT) ? t + 3 : TT - 1;
            const int p3 = A.c.pb[t3][cr];

            f32x4 aRa = __builtin_amdgcn_mfma_f32_16x16x32_f16(Ah[0][0], Bh0, xR1, 0, 0, 0);
            f32x4 aRb = __builtin_amdgcn_mfma_f32_16x16x32_f16(Ah[0][1], Bh1, zero4, 0, 0, 0);
            f32x4 aZ = __builtin_amdgcn_mfma_f32_16x16x32_f16(Ah[1][0], Bh0, xZ1, 0, 0, 0);
            aZ = __builtin_amdgcn_mfma_f32_16x16x32_f16(Ah[1][1], Bh1, aZ, 0, 0, 0);
            f32x4 aH = __builtin_amdgcn_mfma_f32_16x16x32_f16(Ah[2][0], Bh0, biasH, 0, 0, 0);
            aH = __builtin_amdgcn_mfma_f32_16x16x32_f16(Ah[2][1], Bh1, aH, 0, 0, 0);
            const f32x4 aR = aRa + aRb;

            // x(t+2) from BfA (just gathered)
            xR0 = __builtin_amdgcn_mfma_f32_16x16x32_f16(Af[0], BfA, biasR, 0, 0, 0);
            xZ0 = __builtin_amdgcn_mfma_f32_16x16x32_f16(Af[1], BfA, biasZ, 0, 0, 0);
            xX0 = __builtin_amdgcn_mfma_f32_16x16x32_f16(Af[2], BfA, biasX, 0, 0, 0);

            // gather Bf(t+3) -> BfB
            BfB = *(const half8*)&embl[ec][(((p3 >> sh) & mk) + of) * 8];
            uint4* bq = (uint4*)&BfB;
            bq->z = isq2 ? ((unsigned)p3 >> 16) : bq->z;

            ACT_WRITE(aR, aZ, aH, xX1, t + 1 < Ln, 0);
        }
        __syncthreads();
    }
    #undef ACT_WRITE

    const int prow = A.c.Psh[cr];
    *(float2*)&out[prow * HID + j0] = make_float2(h0, h1);
}

extern "C" void kernel_launch(void* const* d_in, const int* in_sizes, int n_in,
                              void* d_out, int out_size, void* d_ws, size_t ws_size,
                              hipStream_t stream) {
    const int*   actor_ids  = (const int*)d_in[0];
    const int*   action_ids = (const int*)d_in[1];
    const int*   street_ids = (const int*)d_in[2];
    const float* bet        = (const float*)d_in[3];
    const int*   vmask      = (const int*)d_in[4];
    const float* E_actor    = (const float*)d_in[5];
    const float* E_action   = (const float*)d_in[6];
    const float* E_street   = (const float*)d_in[7];
    const float* W_proj     = (const float*)d_in[8];
    const float* b_proj     = (const float*)d_in[9];
    const float* W_ih       = (const float*)d_in[10];
    const float* W_hh       = (const float*)d_in[11];
    const float* b_ih       = (const float*)d_in[12];
    const float* b_hh       = (const float*)d_in[13];
    float*       out        = (float*)d_out;

    int* ws   = (int*)d_ws;
    int* lens = ws;
    int* perm = ws + NROWS;

    k_len<<<NROWS / 4, 256, 0, stream>>>(vmask, lens);
    k_sort<<<1, 1024, 0, stream>>>(lens, perm);

    gru_fused<<<NGRP, 256, 0, stream>>>(actor_ids, action_ids, street_ids, bet,
                                        E_actor, E_action, E_street,
                                        W_proj, b_proj, W_ih, b_ih, W_hh, b_hh,
                                        perm, lens, out);
}